// Round 2
// baseline (344.573 us; speedup 1.0000x reference)
//
#include <hip/hip_runtime.h>
#include <hip/hip_bf16.h>

#define BATCH 8
#define CCH 1024
#define NHW 4096
#define SCALE 5.0f   // 1/TEMPERATURE
#define ROWS (BATCH * CCH)

typedef unsigned short u16;
typedef __attribute__((ext_vector_type(8))) short short8;
typedef __attribute__((ext_vector_type(4))) float float4v;

__device__ __forceinline__ void async_load16(const void* gsrc, void* ldst) {
    __builtin_amdgcn_global_load_lds(
        (__attribute__((address_space(1))) void*)gsrc,
        (__attribute__((address_space(3))) void*)ldst,
        16, 0, 0);
}

__device__ __forceinline__ u16 f2bf(float f) {
    union { float f; unsigned int u; } c; c.f = f;
    unsigned int u = c.u;
    unsigned int r = u + 0x7FFFu + ((u >> 16) & 1u);
    return (u16)(r >> 16);
}

// One block per row: diag = sum(x^2)*SCALE, zero l_acc, optionally convert to bf16.
template <bool CONVERT>
__global__ __launch_bounds__(256) void prep_kernel(const float* __restrict__ x,
                                                   u16* __restrict__ xbf,
                                                   float* __restrict__ diag,
                                                   float* __restrict__ l_acc) {
    const int row = blockIdx.x;          // 0..8191
    const int tid = threadIdx.x;
    const float* src = x + (size_t)row * NHW;
    float ssum = 0.f;
#pragma unroll
    for (int p = 0; p < 4; ++p) {
        const int idx = p * 1024 + tid * 4;
        float4 v = *(const float4*)(src + idx);
        ssum += v.x * v.x + v.y * v.y + v.z * v.z + v.w * v.w;
        if (CONVERT) {
            ushort4 o;
            o.x = f2bf(v.x); o.y = f2bf(v.y); o.z = f2bf(v.z); o.w = f2bf(v.w);
            *(ushort4*)(xbf + (size_t)row * NHW + idx) = o;
        }
    }
#pragma unroll
    for (int m = 1; m < 64; m <<= 1) ssum += __shfl_xor(ssum, m);
    __shared__ float red[4];
    if ((tid & 63) == 0) red[tid >> 6] = ssum;
    __syncthreads();
    if (tid == 0) {
        diag[row] = (red[0] + red[1] + red[2] + red[3]) * SCALE;
        l_acc[row] = 0.f;
    }
}

// Symmetric Gram: only tiles with 64-col-block bj2 >= 2*bi (128-row-block bi).
// Tile = 128 rows x 64 cols. Grid = 8 batches * 72 tiles = 576 blocks.
// Epilogue: each element (gr,gc) with gr<=gc contributes exp(5G-diag[gr]) to
// l[gr]; if gr<gc additionally exp(5G-diag[gc]) to l[gc] (col-sum). gr>gc
// elements inside diagonal-straddling tiles are masked out (duplicates).
template <bool BF16SRC>
__global__ __launch_bounds__(256) void gram_kernel(const u16* __restrict__ Xbf,
                                                   const float* __restrict__ Xf,
                                                   const float* __restrict__ diag,
                                                   float* __restrict__ l_acc,
                                                   float* __restrict__ num) {
    __shared__ __align__(16) u16 As[8192];   // 8 kchunks * 128 rows * 8 bf16 = 16KB
    __shared__ __align__(16) u16 Bs[4096];   // 8 kchunks *  64 rows * 8 bf16 = 8KB

    const int bid = blockIdx.x;
    const int b = bid & 7;           // batch in low bits -> XCD spread
    const int t = bid >> 3;          // 0..71 upper-tile index

    int bi = 0;
#pragma unroll
    for (int i = 7; i >= 1; --i) {   // offset(bi) = bi*(17-bi), increasing
        if (t >= i * (17 - i)) { bi = i; break; }
    }
    const int bj2 = 2 * bi + (t - bi * (17 - bi));   // 64-col block, 0..15

    const int tid  = threadIdx.x;
    const int lane = tid & 63;
    const int w    = tid >> 6;       // wave 0..3
    const int wm   = w >> 1;         // wave row-half 0..1 (64 rows each)
    const int wn   = w & 1;          // wave col-half 0..1 (32 cols each)

    const u16*   pA  = nullptr; const u16*   pB  = nullptr;
    const float* pAf = nullptr; const float* pBf = nullptr;
    if (BF16SRC) {
        const u16* baseX = Xbf + (size_t)b * CCH * NHW;
        pA = baseX + (size_t)(bi * 128 + (tid & 127)) * NHW + (tid >> 7) * 8;
        pB = baseX + (size_t)(bj2 * 64 + (tid & 63)) * NHW + (tid >> 6) * 8;
    } else {
        const float* baseXf = Xf + (size_t)b * CCH * NHW;
        pAf = baseXf + (size_t)(bi * 128 + (tid & 127)) * NHW + (tid >> 7) * 8;
        pBf = baseXf + (size_t)(bj2 * 64 + (tid & 63)) * NHW + (tid >> 6) * 8;
    }

    float4v acc[4][2] = {};

    for (int K0 = 0; K0 < NHW; K0 += 64) {
        __syncthreads();   // previous iter's LDS reads complete
        if (BF16SRC) {
#pragma unroll
            for (int ta = 0; ta < 4; ++ta)
                async_load16(pA + ta * 16, As + (size_t)(ta * 256 + w * 64) * 8);
#pragma unroll
            for (int tb = 0; tb < 2; ++tb)
                async_load16(pB + tb * 32, Bs + (size_t)(tb * 256 + w * 64) * 8);
            pA += 64; pB += 64;
        } else {
#pragma unroll
            for (int ta = 0; ta < 4; ++ta) {
                const int c = ta * 256 + tid;
                float4 f0 = *(const float4*)(pAf + ta * 16);
                float4 f1 = *(const float4*)(pAf + ta * 16 + 4);
                u16* d = As + (size_t)c * 8;
                d[0]=f2bf(f0.x); d[1]=f2bf(f0.y); d[2]=f2bf(f0.z); d[3]=f2bf(f0.w);
                d[4]=f2bf(f1.x); d[5]=f2bf(f1.y); d[6]=f2bf(f1.z); d[7]=f2bf(f1.w);
            }
#pragma unroll
            for (int tb = 0; tb < 2; ++tb) {
                const int c = tb * 256 + tid;
                float4 f0 = *(const float4*)(pBf + tb * 32);
                float4 f1 = *(const float4*)(pBf + tb * 32 + 4);
                u16* d = Bs + (size_t)c * 8;
                d[0]=f2bf(f0.x); d[1]=f2bf(f0.y); d[2]=f2bf(f0.z); d[3]=f2bf(f0.w);
                d[4]=f2bf(f1.x); d[5]=f2bf(f1.y); d[6]=f2bf(f1.z); d[7]=f2bf(f1.w);
            }
            pAf += 64; pBf += 64;
        }
        __syncthreads();   // staging visible (vmcnt drained before barrier)

#pragma unroll
        for (int ks = 0; ks < 2; ++ks) {
            short8 af[4], bf[2];
            const int kq = ks * 4 + (lane >> 4);   // kchunk 0..7
            const int rl = lane & 15;
#pragma unroll
            for (int mt = 0; mt < 4; ++mt)
                af[mt] = *(const short8*)(As + (size_t)((kq * 128) + wm * 64 + mt * 16 + rl) * 8);
#pragma unroll
            for (int nt = 0; nt < 2; ++nt)
                bf[nt] = *(const short8*)(Bs + (size_t)((kq * 64) + wn * 32 + nt * 16 + rl) * 8);
#pragma unroll
            for (int mt = 0; mt < 4; ++mt)
#pragma unroll
                for (int nt = 0; nt < 2; ++nt)
                    acc[mt][nt] = __builtin_amdgcn_mfma_f32_16x16x32_bf16(af[mt], bf[nt], acc[mt][nt], 0, 0, 0);
        }
    }

    // ---- Epilogue ----
    const int q  = lane >> 4;    // row-quad 0..3
    const int cl = lane & 15;    // col within 16
    const int rowbase = bi * 128 + wm * 64;
    const int colbase = bj2 * 64 + wn * 32;
    const float* dgb = diag + b * CCH;
    float* lb = l_acc + b * CCH;

    // Row sums (upper-inclusive) + diagonal numerator
#pragma unroll
    for (int mt = 0; mt < 4; ++mt) {
#pragma unroll
        for (int reg = 0; reg < 4; ++reg) {
            const int gr = rowbase + mt * 16 + q * 4 + reg;
            const float dg = dgb[gr];
            float s = 0.f;
#pragma unroll
            for (int nt = 0; nt < 2; ++nt) {
                const int gc = colbase + nt * 16 + cl;
                const float e = __expf(acc[mt][nt][reg] * SCALE - dg);
                if (gr <= gc) s += e;
                if (gr == gc) num[b * CCH + gr] = e;
            }
            s += __shfl_xor(s, 1);
            s += __shfl_xor(s, 2);
            s += __shfl_xor(s, 4);
            s += __shfl_xor(s, 8);
            if (cl == 0) atomicAdd(lb + gr, s);
        }
    }

    // Column sums (strictly-upper -> transposed contribution)
#pragma unroll
    for (int nt = 0; nt < 2; ++nt) {
        const int gc = colbase + nt * 16 + cl;
        const float dgc = dgb[gc];
        float s = 0.f;
#pragma unroll
        for (int mt = 0; mt < 4; ++mt) {
#pragma unroll
            for (int reg = 0; reg < 4; ++reg) {
                const int gr = rowbase + mt * 16 + q * 4 + reg;
                if (gr < gc) s += __expf(acc[mt][nt][reg] * SCALE - dgc);
            }
        }
        s += __shfl_xor(s, 16);
        s += __shfl_xor(s, 32);
        if (lane < 16) atomicAdd(lb + gc, s);
    }
}

__global__ __launch_bounds__(1024) void finalize_kernel(const float* __restrict__ l_acc,
                                                        const float* __restrict__ num,
                                                        float* __restrict__ out) {
    const int tid = threadIdx.x;
    float s = 0.f;
    for (int r = tid; r < ROWS; r += 1024) {
        const float d = num[r] / l_acc[r];
        s += -__logf(d + 1e-10f);
    }
#pragma unroll
    for (int m = 1; m < 64; m <<= 1) s += __shfl_xor(s, m);
    __shared__ float red[16];
    if ((tid & 63) == 0) red[tid >> 6] = s;
    __syncthreads();
    if (tid == 0) {
        float tot = 0.f;
#pragma unroll
        for (int i = 0; i < 16; ++i) tot += red[i];
        out[0] = tot * (1.0f / (float)ROWS);
    }
}

extern "C" void kernel_launch(void* const* d_in, const int* in_sizes, int n_in,
                              void* d_out, int out_size, void* d_ws, size_t ws_size,
                              hipStream_t stream) {
    const float* x = (const float*)d_in[0];
    float* out = (float*)d_out;

    const size_t xbf_bytes  = (size_t)BATCH * CCH * NHW * 2;  // 67108864
    const size_t stat_bytes = (size_t)ROWS * 4;               // 32768
    const bool fast = ws_size >= xbf_bytes + 3 * stat_bytes;

    const int ntiles = 72;  // sum over bi of (16 - 2*bi)

    if (fast) {
        u16*   xbf   = (u16*)d_ws;
        float* diag  = (float*)((char*)d_ws + xbf_bytes);
        float* l_acc = diag + ROWS;
        float* num   = l_acc + ROWS;
        prep_kernel<true><<<ROWS, 256, 0, stream>>>(x, xbf, diag, l_acc);
        gram_kernel<true><<<BATCH * ntiles, 256, 0, stream>>>(xbf, nullptr, diag, l_acc, num);
        finalize_kernel<<<1, 1024, 0, stream>>>(l_acc, num, out);
    } else {
        float* diag  = (float*)d_ws;
        float* l_acc = diag + ROWS;
        float* num   = l_acc + ROWS;
        prep_kernel<false><<<ROWS, 256, 0, stream>>>(x, nullptr, diag, l_acc);
        gram_kernel<false><<<BATCH * ntiles, 256, 0, stream>>>(nullptr, x, diag, l_acc, num);
        finalize_kernel<<<1, 1024, 0, stream>>>(l_acc, num, out);
    }
}

// Round 3
// 255.708 us; speedup vs baseline: 1.3475x; 1.3475x over previous
//
#include <hip/hip_runtime.h>
#include <hip/hip_bf16.h>

#define BATCH 8
#define CCH 1024
#define NHW 4096
#define SCALE 5.0f   // 1/TEMPERATURE
#define ROWS (BATCH * CCH)

typedef unsigned short u16;
typedef __attribute__((ext_vector_type(8))) short short8;
typedef __attribute__((ext_vector_type(4))) float float4v;

__device__ __forceinline__ void async_load16(const void* gsrc, void* ldst) {
    __builtin_amdgcn_global_load_lds(
        (__attribute__((address_space(1))) void*)gsrc,
        (__attribute__((address_space(3))) void*)ldst,
        16, 0, 0);
}

__device__ __forceinline__ u16 f2bf(float f) {
    union { float f; unsigned int u; } c; c.f = f;
    unsigned int u = c.u;
    unsigned int r = u + 0x7FFFu + ((u >> 16) & 1u);
    return (u16)(r >> 16);
}

// One block per row: diag = sum(x^2)*SCALE, zero l_acc, optionally convert to bf16.
template <bool CONVERT>
__global__ __launch_bounds__(256) void prep_kernel(const float* __restrict__ x,
                                                   u16* __restrict__ xbf,
                                                   float* __restrict__ diag,
                                                   float* __restrict__ l_acc) {
    const int row = blockIdx.x;          // 0..8191
    const int tid = threadIdx.x;
    const float* src = x + (size_t)row * NHW;
    float ssum = 0.f;
#pragma unroll
    for (int p = 0; p < 4; ++p) {
        const int idx = p * 1024 + tid * 4;
        float4 v = *(const float4*)(src + idx);
        ssum += v.x * v.x + v.y * v.y + v.z * v.z + v.w * v.w;
        if (CONVERT) {
            ushort4 o;
            o.x = f2bf(v.x); o.y = f2bf(v.y); o.z = f2bf(v.z); o.w = f2bf(v.w);
            *(ushort4*)(xbf + (size_t)row * NHW + idx) = o;
        }
    }
#pragma unroll
    for (int m = 1; m < 64; m <<= 1) ssum += __shfl_xor(ssum, m);
    __shared__ float red[4];
    if ((tid & 63) == 0) red[tid >> 6] = ssum;
    __syncthreads();
    if (tid == 0) {
        diag[row] = (red[0] + red[1] + red[2] + red[3]) * SCALE;
        l_acc[row] = 0.f;
    }
}

// Symmetric Gram, 128x64 tiles over the upper triangle (bj2 >= 2*bi).
// LDS layout XOR-swizzled: chunk (row r, kchunk k) at slot index r*8 + (k^(r&7)),
// each slot 16B. This makes global_load_lds staging coalesced (each row's 8
// slots are a permutation of its contiguous 128B K-span) AND fragment
// ds_read_b128 only 2-way bank-aliased (free).
template <bool BF16SRC>
__global__ __launch_bounds__(256) void gram_kernel(const u16* __restrict__ Xbf,
                                                   const float* __restrict__ Xf,
                                                   const float* __restrict__ diag,
                                                   float* __restrict__ l_acc,
                                                   float* __restrict__ num) {
    __shared__ __align__(16) u16 As[8192];   // 128 rows * 8 slots * 8 u16 = 16KB
    __shared__ __align__(16) u16 Bs[4096];   //  64 rows * 8 slots * 8 u16 = 8KB

    const int bid = blockIdx.x;
    const int b = bid & 7;           // batch in low bits -> XCD spread
    const int t = bid >> 3;          // 0..71 upper-tile index

    int bi = 0;
#pragma unroll
    for (int i = 7; i >= 1; --i) {   // offset(bi) = bi*(17-bi), increasing
        if (t >= i * (17 - i)) { bi = i; break; }
    }
    const int bj2 = 2 * bi + (t - bi * (17 - bi));   // 64-col block, 0..15

    const int tid  = threadIdx.x;
    const int lane = tid & 63;
    const int w    = tid >> 6;       // wave 0..3
    const int wm   = w >> 1;         // wave row-half 0..1 (64 rows each)
    const int wn   = w & 1;          // wave col-half 0..1 (32 cols each)

    // Staging lane mapping: within a wave-instruction, lane i covers
    // row_local = i>>3, slot = i&7, global kchunk = (i&7) ^ ((i>>3)&7).
    const int st_r  = lane >> 3;                 // 0..7 row within 8-row group
    const int st_kc = (lane & 7) ^ (st_r & 7);   // swizzled source kchunk

    const u16*   pA  = nullptr; const u16*   pB  = nullptr;
    const float* pAf = nullptr; const float* pBf = nullptr;
    if (BF16SRC) {
        const u16* baseX = Xbf + (size_t)b * CCH * NHW;
        // A: wave w stages rows w*32 + t8*8 + st_r (t8=0..3)
        pA = baseX + (size_t)(bi * 128 + w * 32 + st_r) * NHW + st_kc * 8;
        // B: wave w stages rows w*16 + t8*8 + st_r (t8=0..1)
        pB = baseX + (size_t)(bj2 * 64 + w * 16 + st_r) * NHW + st_kc * 8;
    } else {
        const float* baseXf = Xf + (size_t)b * CCH * NHW;
        pAf = baseXf + (size_t)(bi * 128 + w * 32 + st_r) * NHW + st_kc * 8;
        pBf = baseXf + (size_t)(bj2 * 64 + w * 16 + st_r) * NHW + st_kc * 8;
    }

    float4v acc[4][2] = {};

    for (int K0 = 0; K0 < NHW; K0 += 64) {
        __syncthreads();   // previous iter's LDS reads complete
        if (BF16SRC) {
#pragma unroll
            for (int t8 = 0; t8 < 4; ++t8)     // A: 8 rows per instr, 32 rows per wave
                async_load16(pA + (size_t)t8 * 8 * NHW,
                             As + (size_t)(w * 32 + t8 * 8) * 64);
#pragma unroll
            for (int t8 = 0; t8 < 2; ++t8)     // B: 16 rows per wave
                async_load16(pB + (size_t)t8 * 8 * NHW,
                             Bs + (size_t)(w * 16 + t8 * 8) * 64);
            pA += 64; pB += 64;
        } else {
#pragma unroll
            for (int t8 = 0; t8 < 4; ++t8) {
                const float* s = pAf + (size_t)t8 * 8 * NHW;
                float4 f0 = *(const float4*)(s);
                float4 f1 = *(const float4*)(s + 4);
                u16* d = As + (size_t)(w * 32 + t8 * 8 + st_r) * 64 + (lane & 7) * 8;
                d[0]=f2bf(f0.x); d[1]=f2bf(f0.y); d[2]=f2bf(f0.z); d[3]=f2bf(f0.w);
                d[4]=f2bf(f1.x); d[5]=f2bf(f1.y); d[6]=f2bf(f1.z); d[7]=f2bf(f1.w);
            }
#pragma unroll
            for (int t8 = 0; t8 < 2; ++t8) {
                const float* s = pBf + (size_t)t8 * 8 * NHW;
                float4 f0 = *(const float4*)(s);
                float4 f1 = *(const float4*)(s + 4);
                u16* d = Bs + (size_t)(w * 16 + t8 * 8 + st_r) * 64 + (lane & 7) * 8;
                d[0]=f2bf(f0.x); d[1]=f2bf(f0.y); d[2]=f2bf(f0.z); d[3]=f2bf(f0.w);
                d[4]=f2bf(f1.x); d[5]=f2bf(f1.y); d[6]=f2bf(f1.z); d[7]=f2bf(f1.w);
            }
            pAf += 64; pBf += 64;
        }
        __syncthreads();   // staging visible (vmcnt drained before barrier)

#pragma unroll
        for (int ks = 0; ks < 2; ++ks) {
            short8 af[4], bf[2];
            const int kq = ks * 4 + (lane >> 4);        // kchunk 0..7
            const int rl = lane & 15;
            const int slot = kq ^ (rl & 7);             // swizzled slot (uniform over mt/nt)
#pragma unroll
            for (int mt = 0; mt < 4; ++mt)
                af[mt] = *(const short8*)(As + (size_t)(wm * 64 + mt * 16 + rl) * 64 + slot * 8);
#pragma unroll
            for (int nt = 0; nt < 2; ++nt)
                bf[nt] = *(const short8*)(Bs + (size_t)(wn * 32 + nt * 16 + rl) * 64 + slot * 8);
#pragma unroll
            for (int mt = 0; mt < 4; ++mt)
#pragma unroll
                for (int nt = 0; nt < 2; ++nt)
                    acc[mt][nt] = __builtin_amdgcn_mfma_f32_16x16x32_bf16(af[mt], bf[nt], acc[mt][nt], 0, 0, 0);
        }
    }

    // ---- Epilogue ----
    const int q  = lane >> 4;    // row-quad 0..3
    const int cl = lane & 15;    // col within 16
    const int rowbase = bi * 128 + wm * 64;
    const int colbase = bj2 * 64 + wn * 32;
    const float* dgb = diag + b * CCH;
    float* lb = l_acc + b * CCH;

    // Row sums (upper-inclusive) + diagonal numerator
#pragma unroll
    for (int mt = 0; mt < 4; ++mt) {
#pragma unroll
        for (int reg = 0; reg < 4; ++reg) {
            const int gr = rowbase + mt * 16 + q * 4 + reg;
            const float dg = dgb[gr];
            float s = 0.f;
#pragma unroll
            for (int nt = 0; nt < 2; ++nt) {
                const int gc = colbase + nt * 16 + cl;
                const float e = __expf(acc[mt][nt][reg] * SCALE - dg);
                if (gr <= gc) s += e;
                if (gr == gc) num[b * CCH + gr] = e;
            }
            s += __shfl_xor(s, 1);
            s += __shfl_xor(s, 2);
            s += __shfl_xor(s, 4);
            s += __shfl_xor(s, 8);
            if (cl == 0) atomicAdd(lb + gr, s);
        }
    }

    // Column sums (strictly-upper -> transposed contribution)
#pragma unroll
    for (int nt = 0; nt < 2; ++nt) {
        const int gc = colbase + nt * 16 + cl;
        const float dgc = dgb[gc];
        float s = 0.f;
#pragma unroll
        for (int mt = 0; mt < 4; ++mt) {
#pragma unroll
            for (int reg = 0; reg < 4; ++reg) {
                const int gr = rowbase + mt * 16 + q * 4 + reg;
                if (gr < gc) s += __expf(acc[mt][nt][reg] * SCALE - dgc);
            }
        }
        s += __shfl_xor(s, 16);
        s += __shfl_xor(s, 32);
        if (lane < 16) atomicAdd(lb + gc, s);
    }
}

__global__ __launch_bounds__(1024) void finalize_kernel(const float* __restrict__ l_acc,
                                                        const float* __restrict__ num,
                                                        float* __restrict__ out) {
    const int tid = threadIdx.x;
    float s = 0.f;
    for (int r = tid; r < ROWS; r += 1024) {
        const float d = num[r] / l_acc[r];
        s += -__logf(d + 1e-10f);
    }
#pragma unroll
    for (int m = 1; m < 64; m <<= 1) s += __shfl_xor(s, m);
    __shared__ float red[16];
    if ((tid & 63) == 0) red[tid >> 6] = s;
    __syncthreads();
    if (tid == 0) {
        float tot = 0.f;
#pragma unroll
        for (int i = 0; i < 16; ++i) tot += red[i];
        out[0] = tot * (1.0f / (float)ROWS);
    }
}

extern "C" void kernel_launch(void* const* d_in, const int* in_sizes, int n_in,
                              void* d_out, int out_size, void* d_ws, size_t ws_size,
                              hipStream_t stream) {
    const float* x = (const float*)d_in[0];
    float* out = (float*)d_out;

    const size_t xbf_bytes  = (size_t)BATCH * CCH * NHW * 2;  // 67108864
    const size_t stat_bytes = (size_t)ROWS * 4;               // 32768
    const bool fast = ws_size >= xbf_bytes + 3 * stat_bytes;

    const int ntiles = 72;  // sum over bi of (16 - 2*bi)

    if (fast) {
        u16*   xbf   = (u16*)d_ws;
        float* diag  = (float*)((char*)d_ws + xbf_bytes);
        float* l_acc = diag + ROWS;
        float* num   = l_acc + ROWS;
        prep_kernel<true><<<ROWS, 256, 0, stream>>>(x, xbf, diag, l_acc);
        gram_kernel<true><<<BATCH * ntiles, 256, 0, stream>>>(xbf, nullptr, diag, l_acc, num);
        finalize_kernel<<<1, 1024, 0, stream>>>(l_acc, num, out);
    } else {
        float* diag  = (float*)d_ws;
        float* l_acc = diag + ROWS;
        float* num   = l_acc + ROWS;
        prep_kernel<false><<<ROWS, 256, 0, stream>>>(x, nullptr, diag, l_acc);
        gram_kernel<false><<<BATCH * ntiles, 256, 0, stream>>>(nullptr, x, diag, l_acc, num);
        finalize_kernel<<<1, 1024, 0, stream>>>(l_acc, num, out);
    }
}